// Round 6
// baseline (849.539 us; speedup 1.0000x reference)
//
#include <hip/hip_runtime.h>
#include <hip/hip_cooperative_groups.h>

namespace cg = cooperative_groups;

#define NN 40000
#define NE 640000
#define DF 128
#define NG 2000
#define NCH 157          // ceil(NN/256)
#define CCH (NE / 256)   // 2500 edge chunks
#define GEMM_BLKS 313    // ceil(NN/128)

typedef unsigned int u32;
typedef __attribute__((ext_vector_type(8))) short short8;
typedef __attribute__((ext_vector_type(4))) float floatx4;

// ---- bf16 helpers (packed u32: low 16 = even col, high = odd col) ----
__device__ inline float2 bf2_to_f2(u32 u) {
    return make_float2(__uint_as_float(u << 16), __uint_as_float(u & 0xffff0000u));
}
__device__ inline u32 f_to_bf(float f) {
    u32 u = __float_as_uint(f);
    return (u + 0x7fffu + ((u >> 16) & 1u)) >> 16;   // RNE
}
__device__ inline u32 pack_bf2(float a, float b) {
    return f_to_bf(a) | (f_to_bf(b) << 16);
}
__device__ inline float bf_to_f(short s) {
    return __uint_as_float(((u32)(unsigned short)s) << 16);
}

struct Args {
    const float* x;
    const int* src; const int* dst; const int* batch;
    const float* W1; const float* b1; const float* W2; const float* b2;
    const float* bn1g; const float* bn1b; const float* bn2g; const float* bn2b;
    const float* fc1w; const float* fc1b; const float* fc2w; const float* fc2b;
    const float* fc3w; const float* fc3b;
    int* deg; int* row_ptr; int* cursor; int* col; float* dis;
    unsigned short* wt1; unsigned short* wt2;
    u32* bufA; u32* bufB;
    float* slotsA; float* slotsB;
    float* out;
};

// ---------------- MFMA GEMM tile: 128 rows x 128 cols; 4 waves, wave w rows w*32..+31 ----------------
// LDS: wlds (Wt staged) and clds (C epilogue) UNION in sbuf (extra barrier between uses).
template<bool BF16IN, bool FUSE_BN>
__device__ void gemm_tile(const void* __restrict__ Xv, const unsigned short* __restrict__ wt,
                          u32* __restrict__ outb, int tile, int tid, char* sbuf,
                          const float* sc, const float* sh) {
    unsigned short* wlds = (unsigned short*)sbuf;   // [128][136]
    unsigned short* clds = (unsigned short*)sbuf;   // union, reused after barrier
    int row0 = tile * 128;

    for (int i = tid; i < 2048; i += 256) {
        int c = i >> 4, s = i & 15;
        *(uint4*)&wlds[c * 136 + s * 8] = ((const uint4*)wt)[i];
    }
    __syncthreads();

    int lane = tid & 63;
    int wave = tid >> 6;
    int qr = lane >> 4;        // quad: k-offset qr*8
    int rl = lane & 15;        // A row / B col within 16-tile
    int rA0 = row0 + wave * 32 + rl;
    int rA1 = rA0 + 16;
    int rA0c = rA0 < NN ? rA0 : NN - 1;
    int rA1c = rA1 < NN ? rA1 : NN - 1;

    floatx4 acc[2][8];
#pragma unroll
    for (int a = 0; a < 2; a++)
#pragma unroll
        for (int b = 0; b < 8; b++) acc[a][b] = (floatx4){0.f, 0.f, 0.f, 0.f};

#pragma unroll
    for (int kb = 0; kb < 4; kb++) {
        int k0 = kb * 32 + qr * 8;
        short8 a0, a1;
        if (!BF16IN) {
            const float* p0 = (const float*)Xv + (size_t)rA0c * DF + k0;
            const float* p1 = (const float*)Xv + (size_t)rA1c * DF + k0;
            float4 u0 = *(const float4*)p0, u1 = *(const float4*)(p0 + 4);
            float4 v0 = *(const float4*)p1, v1 = *(const float4*)(p1 + 4);
            float fa[8] = {u0.x, u0.y, u0.z, u0.w, u1.x, u1.y, u1.z, u1.w};
            float fb[8] = {v0.x, v0.y, v0.z, v0.w, v1.x, v1.y, v1.z, v1.w};
#pragma unroll
            for (int j = 0; j < 8; j++) { a0[j] = (short)f_to_bf(fa[j]); a1[j] = (short)f_to_bf(fb[j]); }
        } else {
            a0 = *(const short8*)((const u32*)Xv + (size_t)rA0c * 64 + (k0 >> 1));
            a1 = *(const short8*)((const u32*)Xv + (size_t)rA1c * 64 + (k0 >> 1));
            if (FUSE_BN) {
#pragma unroll
                for (int j = 0; j < 8; j++) {
                    float f0 = fmaxf(fmaf(bf_to_f(a0[j]), sc[k0 + j], sh[k0 + j]), 0.f);
                    float f1 = fmaxf(fmaf(bf_to_f(a1[j]), sc[k0 + j], sh[k0 + j]), 0.f);
                    a0[j] = (short)f_to_bf(f0);
                    a1[j] = (short)f_to_bf(f1);
                }
            }
        }
#pragma unroll
        for (int ct = 0; ct < 8; ct++) {
            short8 bfr = *(const short8*)&wlds[(ct * 16 + rl) * 136 + k0];
            acc[0][ct] = __builtin_amdgcn_mfma_f32_16x16x32_bf16(a0, bfr, acc[0][ct], 0, 0, 0);
            acc[1][ct] = __builtin_amdgcn_mfma_f32_16x16x32_bf16(a1, bfr, acc[1][ct], 0, 0, 0);
        }
    }
    __syncthreads();   // all wlds reads complete before clds overwrites the union
    // C/D layout: col=lane&15, row=quad*4+reg
#pragma unroll
    for (int rt = 0; rt < 2; rt++)
#pragma unroll
        for (int ct = 0; ct < 8; ct++)
#pragma unroll
            for (int r = 0; r < 4; r++) {
                int lr = wave * 32 + rt * 16 + qr * 4 + r;
                int c = ct * 16 + rl;
                clds[lr * 136 + c] = (unsigned short)f_to_bf(acc[rt][ct][r]);
            }
    __syncthreads();
    for (int i = tid; i < 2048; i += 256) {
        int lr = i >> 4, s = i & 15;
        int grow = row0 + lr;
        if (grow < NN) {
            uint4 v = *(const uint4*)&clds[lr * 136 + s * 8];
            ((uint4*)(outb + (size_t)grow * 64))[s] = v;
        }
    }
    __syncthreads();   // safe LDS reuse next tile
}

// ---------------- gather group: 4 nodes (one per wave); BN stats fused ----------------
__device__ void gather_group(const u32* __restrict__ Hb, const int* __restrict__ row_ptr,
                             const int* __restrict__ col, const float* __restrict__ dis,
                             const float* __restrict__ bias, u32* __restrict__ outb,
                             float* __restrict__ slots, int g4, int tid, char* sbuf) {
    float* sred = (float*)sbuf;        // [4][128]
    float* qred = sred + 512;          // [4][128]
    int t = tid & 63;                  // lane: cols 2t, 2t+1
    int wv = tid >> 6;
    int node = g4 * 4 + wv;
    float di = dis[node];
    float2 acc;
    {
        float2 a = bf2_to_f2(Hb[(size_t)node * 64 + t]);
        float s = di * di;
        acc = make_float2(a.x * s, a.y * s);
    }
    int lo = row_ptr[node], hi = row_ptr[node + 1];
    for (int base = lo; base < hi; base += 64) {
        int m = hi - base; if (m > 64) m = 64;
        int sidx = 0; float sw = 0.f;
        if (t < m) { sidx = col[base + t]; sw = di * dis[sidx]; }
        int j = 0;
        for (; j + 4 <= m; j += 4) {
            int s0 = __shfl(sidx, j),     s1 = __shfl(sidx, j + 1);
            int s2 = __shfl(sidx, j + 2), s3 = __shfl(sidx, j + 3);
            float w0 = __shfl(sw, j),     w1 = __shfl(sw, j + 1);
            float w2 = __shfl(sw, j + 2), w3 = __shfl(sw, j + 3);
            float2 h0 = bf2_to_f2(Hb[(size_t)s0 * 64 + t]);
            float2 h1 = bf2_to_f2(Hb[(size_t)s1 * 64 + t]);
            float2 h2 = bf2_to_f2(Hb[(size_t)s2 * 64 + t]);
            float2 h3 = bf2_to_f2(Hb[(size_t)s3 * 64 + t]);
            acc.x = fmaf(h3.x, w3, fmaf(h2.x, w2, fmaf(h1.x, w1, fmaf(h0.x, w0, acc.x))));
            acc.y = fmaf(h3.y, w3, fmaf(h2.y, w2, fmaf(h1.y, w1, fmaf(h0.y, w0, acc.y))));
        }
        for (; j < m; j++) {
            int s0 = __shfl(sidx, j); float w0 = __shfl(sw, j);
            float2 h0 = bf2_to_f2(Hb[(size_t)s0 * 64 + t]);
            acc.x = fmaf(h0.x, w0, acc.x);
            acc.y = fmaf(h0.y, w0, acc.y);
        }
    }
    float2 b = ((const float2*)bias)[t];
    acc.x += b.x; acc.y += b.y;
    outb[(size_t)node * 64 + t] = pack_bf2(acc.x, acc.y);
    sred[wv * 128 + 2 * t] = acc.x;         sred[wv * 128 + 2 * t + 1] = acc.y;
    qred[wv * 128 + 2 * t] = acc.x * acc.x; qred[wv * 128 + 2 * t + 1] = acc.y * acc.y;
    __syncthreads();
    if (tid < 128) {
        float s = sred[tid] + sred[128 + tid] + sred[256 + tid] + sred[384 + tid];
        float q = qred[tid] + qred[128 + tid] + qred[256 + tid] + qred[384 + tid];
        int slot = g4 & 63;
        atomicAdd(&slots[slot * 256 + tid], s);
        atomicAdd(&slots[slot * 256 + 128 + tid], q);
    }
    __syncthreads();
}

// ---------------- BN coefficients from 64-slot partials ----------------
__device__ void bn_coeffs(const float* __restrict__ slots, const float* __restrict__ gam,
                          const float* __restrict__ bet, float* sc, float* sh, int tid) {
    if (tid < 128) {
        float s = 0.f, q = 0.f;
        for (int k = 0; k < 64; k++) {
            s += slots[k * 256 + tid];
            q += slots[k * 256 + 128 + tid];
        }
        const float inv_n = 1.0f / (float)NN;
        float mu = s * inv_n;
        float va = fmaf(-mu, mu, q * inv_n);
        float a = gam[tid] * rsqrtf(va + 1e-5f);
        sc[tid] = a;
        sh[tid] = fmaf(-mu, a, bet[tid]);
    }
}

// ---------------- pool (BN2+ReLU) + fc1 + fc2 + fc3 for 4 graphs ----------------
__device__ void poolfc_group(const u32* __restrict__ Hb, const int* __restrict__ batch,
                             const float* sc, const float* sh,
                             const float* __restrict__ fc1w, const float* __restrict__ fc1b,
                             const float* __restrict__ fc2w, const float* __restrict__ fc2b,
                             const float* __restrict__ fc3w, const float* __restrict__ fc3b,
                             float* __restrict__ out, int gb, int tid, char* sbuf) {
    float* pooled = (float*)sbuf;          // [4][128]
    float* g1 = pooled + 512;              // [4][256]
    float* g2 = g1 + 1024;                 // [4][256]
    int* bnds = (int*)(g2 + 1024);         // [5]
    int gbase = gb * 4;
    if (tid < 5) {
        int target = gbase + tid;
        int a = 0, b = NN;
        while (a < b) { int m = (a + b) >> 1; if (batch[m] < target) a = m + 1; else b = m; }
        bnds[tid] = a;
    }
    __syncthreads();
    {
        int g = tid >> 6, p = tid & 63;
        int lo = bnds[g], hi = bnds[g + 1];
        float a0 = 0.f, a1 = 0.f;
        float sc0 = sc[2 * p], sh0 = sh[2 * p], sc1 = sc[2 * p + 1], sh1 = sh[2 * p + 1];
        for (int i = lo; i < hi; i++) {
            float2 v = bf2_to_f2(Hb[(size_t)i * 64 + p]);
            a0 += fmaxf(fmaf(v.x, sc0, sh0), 0.f);
            a1 += fmaxf(fmaf(v.y, sc1, sh1), 0.f);
        }
        pooled[g * 128 + 2 * p] = a0;
        pooled[g * 128 + 2 * p + 1] = a1;
    }
    __syncthreads();
    {
        float x0 = 0.f, x1 = 0.f, x2 = 0.f, x3 = 0.f;
        for (int k = 0; k < 128; k++) {
            float wv = fc1w[k * 256 + tid];
            x0 = fmaf(pooled[k], wv, x0);
            x1 = fmaf(pooled[128 + k], wv, x1);
            x2 = fmaf(pooled[256 + k], wv, x2);
            x3 = fmaf(pooled[384 + k], wv, x3);
        }
        float bb = fc1b[tid];
        g1[tid] = fmaxf(x0 + bb, 0.f);
        g1[256 + tid] = fmaxf(x1 + bb, 0.f);
        g1[512 + tid] = fmaxf(x2 + bb, 0.f);
        g1[768 + tid] = fmaxf(x3 + bb, 0.f);
    }
    __syncthreads();
    {
        float x0 = 0.f, x1 = 0.f, x2 = 0.f, x3 = 0.f;
        for (int k = 0; k < 256; k++) {
            float wv = fc2w[k * 256 + tid];
            x0 = fmaf(g1[k], wv, x0);
            x1 = fmaf(g1[256 + k], wv, x1);
            x2 = fmaf(g1[512 + k], wv, x2);
            x3 = fmaf(g1[768 + k], wv, x3);
        }
        float bb = fc2b[tid];
        g2[tid] = fmaxf(x0 + bb, 0.f);
        g2[256 + tid] = fmaxf(x1 + bb, 0.f);
        g2[512 + tid] = fmaxf(x2 + bb, 0.f);
        g2[768 + tid] = fmaxf(x3 + bb, 0.f);
    }
    __syncthreads();
    {
        int lane = tid & 63, wv = tid >> 6;
        const float* row = g2 + wv * 256;
        float s = fmaf(row[lane], fc3w[lane],
                  fmaf(row[64 + lane], fc3w[64 + lane],
                  fmaf(row[128 + lane], fc3w[128 + lane],
                       row[192 + lane] * fc3w[192 + lane])));
        for (int off = 32; off > 0; off >>= 1) s += __shfl_down(s, off);
        if (lane == 0) out[gbase + wv] = s + fc3b[0];
    }
    __syncthreads();
}

// ================= single cooperative mega-kernel =================
__global__ __launch_bounds__(256, 4) void k_mega(Args a) {
    __shared__ __align__(16) char sbuf[34816];   // wlds/clds union; also scan/gather/poolfc scratch
    __shared__ float sc[128], sh[128];
    cg::grid_group grid = cg::this_grid();
    const int tid = threadIdx.x;
    const int bid = blockIdx.x;
    const int nb = gridDim.x;

    // ---- phase 0: zero deg/slots; W1,W2 -> bf16 transposed ----
    for (int i = bid * 256 + tid; i < NN; i += nb * 256) a.deg[i] = 0;
    for (int i = bid * 256 + tid; i < 64 * 256; i += nb * 256) { a.slotsA[i] = 0.f; a.slotsB[i] = 0.f; }
    for (int i = bid * 256 + tid; i < 2 * 16384; i += nb * 256) {
        int w = i >> 14, idx = i & 16383;
        int k = idx >> 7, c = idx & 127;
        const float* W = w ? a.W2 : a.W1;
        unsigned short* wt = w ? a.wt2 : a.wt1;
        wt[c * 128 + k] = (unsigned short)f_to_bf(W[idx]);
    }
    grid.sync();

    // ---- phase 1: degree count (2500 chunks) + GEMM1 (313 tiles), independent work mixed ----
    for (int item = bid; item < CCH + GEMM_BLKS; item += nb) {
        if (item < CCH) {
            int e = item * 256 + tid;
            atomicAdd(&a.deg[a.dst[e]], 1);
        } else {
            gemm_tile<false, false>(a.x, a.wt1, a.bufA, item - CCH, tid, sbuf, sc, sh);
        }
    }
    grid.sync();

    // ---- phase 2: scan (157 blocks; block b redundantly sums deg[0..256b), coalesced L2 reads) ----
    if (bid < NCH) {
        int* red = (int*)sbuf;
        int* ls = red + 256;
        int limit = bid * 256;
        int partial = 0;
        for (int i = tid; i < limit; i += 256) partial += a.deg[i];
        red[tid] = partial;
        int i = limit + tid;
        int d = (i < NN) ? a.deg[i] : 0;
        ls[tid] = d;
        __syncthreads();
#pragma unroll
        for (int off = 128; off > 0; off >>= 1) {
            if (tid < off) red[tid] += red[tid + off];
            __syncthreads();
        }
        int base = red[0];
#pragma unroll
        for (int off = 1; off < 256; off <<= 1) {
            int t2 = (tid >= off) ? ls[tid - off] : 0;
            __syncthreads();
            ls[tid] += t2;
            __syncthreads();
        }
        if (i < NN) {
            int r = base + ls[tid] - d;
            a.row_ptr[i] = r;
            a.cursor[i] = r;
            a.dis[i] = rsqrtf((float)(d + 1));
        }
        if (bid == NCH - 1 && tid == 0) a.row_ptr[NN] = NE;
    }
    grid.sync();

    // ---- phase 3: CSR fill ----
    for (int item = bid; item < CCH; item += nb) {
        int e = item * 256 + tid;
        int p = atomicAdd(&a.cursor[a.dst[e]], 1);
        a.col[p] = a.src[e];
    }
    grid.sync();

    // ---- phase 4: gather1 (+BN1 stats) ----
    for (int g4 = bid; g4 < NN / 4; g4 += nb)
        gather_group(a.bufA, a.row_ptr, a.col, a.dis, a.b1, a.bufB, a.slotsA, g4, tid, sbuf);
    grid.sync();

    // ---- phase 5: GEMM2 with fused BN1+ReLU ----
    bn_coeffs(a.slotsA, a.bn1g, a.bn1b, sc, sh, tid);
    __syncthreads();
    for (int t2 = bid; t2 < GEMM_BLKS; t2 += nb)
        gemm_tile<true, true>(a.bufB, a.wt2, a.bufA, t2, tid, sbuf, sc, sh);
    grid.sync();

    // ---- phase 6: gather2 (+BN2 stats) ----
    for (int g4 = bid; g4 < NN / 4; g4 += nb)
        gather_group(a.bufA, a.row_ptr, a.col, a.dis, a.b2, a.bufB, a.slotsB, g4, tid, sbuf);
    grid.sync();

    // ---- phase 7: pool (BN2+ReLU) + MLP head ----
    bn_coeffs(a.slotsB, a.bn2g, a.bn2b, sc, sh, tid);
    __syncthreads();
    for (int gb = bid; gb < NG / 4; gb += nb)
        poolfc_group(a.bufB, a.batch, sc, sh, a.fc1w, a.fc1b, a.fc2w, a.fc2b,
                     a.fc3w, a.fc3b, a.out, gb, tid, sbuf);
}

extern "C" void kernel_launch(void* const* d_in, const int* in_sizes, int n_in,
                              void* d_out, int out_size, void* d_ws, size_t ws_size,
                              hipStream_t stream) {
    const int* ei = (const int*)d_in[1];

    char* w = (char*)d_ws;
    size_t o = 0;
    auto alloc = [&](size_t bytes) -> char* {
        char* p = w + o;
        o = (o + bytes + 255) & ~(size_t)255;
        return p;
    };
    int* deg = (int*)alloc((size_t)NN * 4);
    float* slotsA = (float*)alloc(64 * 256 * 4);
    float* slotsB = (float*)alloc(64 * 256 * 4);
    int* row_ptr = (int*)alloc((size_t)(NN + 1) * 4);
    int* cursor = (int*)alloc((size_t)NN * 4);
    int* col = (int*)alloc((size_t)NE * 4);
    float* dis = (float*)alloc((size_t)NN * 4);
    unsigned short* wt1 = (unsigned short*)alloc(128 * 128 * 2);
    unsigned short* wt2 = (unsigned short*)alloc(128 * 128 * 2);
    u32* bufA = (u32*)alloc((size_t)NN * 64 * 4);
    u32* bufB = (u32*)alloc((size_t)NN * 64 * 4);

    Args args;
    args.x = (const float*)d_in[0];
    args.src = ei;
    args.dst = ei + NE;
    args.batch = (const int*)d_in[2];
    args.W1 = (const float*)d_in[4];  args.b1 = (const float*)d_in[5];
    args.W2 = (const float*)d_in[6];  args.b2 = (const float*)d_in[7];
    args.bn1g = (const float*)d_in[8];  args.bn1b = (const float*)d_in[9];
    args.bn2g = (const float*)d_in[10]; args.bn2b = (const float*)d_in[11];
    args.fc1w = (const float*)d_in[12]; args.fc1b = (const float*)d_in[13];
    args.fc2w = (const float*)d_in[14]; args.fc2b = (const float*)d_in[15];
    args.fc3w = (const float*)d_in[16]; args.fc3b = (const float*)d_in[17];
    args.deg = deg; args.row_ptr = row_ptr; args.cursor = cursor; args.col = col;
    args.dis = dis; args.wt1 = wt1; args.wt2 = wt2;
    args.bufA = bufA; args.bufB = bufB;
    args.slotsA = slotsA; args.slotsB = slotsB;
    args.out = (float*)d_out;

    int blocksPerCU = 0;
    hipOccupancyMaxActiveBlocksPerMultiprocessor(&blocksPerCU, k_mega, 256, 0);
    if (blocksPerCU < 1) blocksPerCU = 1;
    int grid = blocksPerCU * 256;
    if (grid > 1024) grid = 1024;
    if (grid < 256) grid = 256;   // scan needs >=157 blocks

    void* params[] = { &args };
    hipLaunchCooperativeKernel(k_mega, dim3(grid), dim3(256), params, 0, stream);
}

// Round 7
// 306.238 us; speedup vs baseline: 2.7741x; 2.7741x over previous
//
#include <hip/hip_runtime.h>

#define NN 40000
#define NE 640000
#define DF 128
#define NG 2000
#define NCH 157   // ceil(NN/256) chunks

typedef unsigned int u32;
typedef __attribute__((ext_vector_type(8))) short short8;
typedef __attribute__((ext_vector_type(4))) float floatx4;

// ---- bf16 helpers (packed u32: low 16 = even col, high = odd col) ----
__device__ inline float2 bf2_to_f2(u32 u) {
    return make_float2(__uint_as_float(u << 16), __uint_as_float(u & 0xffff0000u));
}
__device__ inline u32 f_to_bf(float f) {
    u32 u = __float_as_uint(f);
    return (u + 0x7fffu + ((u >> 16) & 1u)) >> 16;   // RNE
}
__device__ inline u32 pack_bf2(float a, float b) {
    return f_to_bf(a) | (f_to_bf(b) << 16);
}
__device__ inline float bf_to_f(short s) {
    return __uint_as_float(((u32)(unsigned short)s) << 16);
}

// ---------------- count (2500 blocks) + W->bf16 transpose (2 blocks) ----------------
__global__ __launch_bounds__(256) void k_count(const int* __restrict__ dst, int* __restrict__ deg,
                                               const float* __restrict__ W1, const float* __restrict__ W2,
                                               unsigned short* __restrict__ wt1, unsigned short* __restrict__ wt2) {
    int bid = blockIdx.x;
    if (bid < NE / 256) {
        int e = bid * 256 + threadIdx.x;
        atomicAdd(&deg[dst[e]], 1);   // 40000 addresses, ~16 ops each: benign
        return;
    }
    const float* W = (bid == NE / 256) ? W1 : W2;
    unsigned short* wt = (bid == NE / 256) ? wt1 : wt2;
    for (int i = threadIdx.x; i < 128 * 128; i += 256) {
        int k = i >> 7, c = i & 127;
        wt[c * 128 + k] = (unsigned short)f_to_bf(W[i]);   // Wt[c][k] = W[k][c]
    }
}

// ---------------- scan: 157 blocks; block b redundantly sums deg[0..256b) (coalesced,
// L2-hot, no atomics, no cross-block sync), then LDS-scans its own chunk ----------------
__global__ __launch_bounds__(256) void k_scan(const int* __restrict__ deg,
                                              int* __restrict__ row_ptr, int* __restrict__ cursor,
                                              float* __restrict__ dis) {
    __shared__ int red[256];
    __shared__ int ls[256];
    int tid = threadIdx.x;
    int blk = blockIdx.x;
    int limit = blk * 256;
    int partial = 0;
    for (int i = tid; i < limit; i += 256) partial += deg[i];
    red[tid] = partial;
    int i = limit + tid;
    int d = (i < NN) ? deg[i] : 0;
    ls[tid] = d;
    __syncthreads();
#pragma unroll
    for (int off = 128; off > 0; off >>= 1) {
        if (tid < off) red[tid] += red[tid + off];
        __syncthreads();
    }
    int base = red[0];
#pragma unroll
    for (int off = 1; off < 256; off <<= 1) {
        int t = (tid >= off) ? ls[tid - off] : 0;
        __syncthreads();
        ls[tid] += t;
        __syncthreads();
    }
    if (i < NN) {
        int r = base + ls[tid] - d;   // global exclusive prefix
        row_ptr[i] = r;
        cursor[i] = r;
        dis[i] = rsqrtf((float)(d + 1));
    }
    if (blk == NCH - 1 && tid == 0) row_ptr[NN] = NE;
}

// ---------------- MFMA GEMM core: out[NxDF bf16] = act(X) @ W (Wt bf16 pre-transposed) ----------------
// block 256 thr (4 waves); tile 128 rows x 128 cols; wave w rows w*32..+31, all 128 cols.
// LDS: single 34816B buffer, wlds (W stage) UNION clds (C epilogue) -> 4 blocks/CU.
template<bool BF16IN, bool FUSE_BN>
__device__ __forceinline__ void gemm_core(const void* __restrict__ Xv, const unsigned short* __restrict__ wt,
                                          u32* __restrict__ outb, const float* __restrict__ slots,
                                          const float* __restrict__ gam, const float* __restrict__ bet, int bid) {
    __shared__ unsigned short uni[128 * 136];   // wlds / clds union
    __shared__ float sc[128], sh[128];
    unsigned short* wlds = uni;
    unsigned short* clds = uni;
    int tid = threadIdx.x;
    int row0 = bid * 128;

    if (FUSE_BN) {
        if (tid < 128) {
            float s = 0.f, q = 0.f;
            for (int k = 0; k < 64; k++) {
                s += slots[k * 256 + tid];
                q += slots[k * 256 + 128 + tid];
            }
            const float inv_n = 1.0f / (float)NN;
            float mu = s * inv_n;
            float va = fmaf(-mu, mu, q * inv_n);
            float a = gam[tid] * rsqrtf(va + 1e-5f);
            sc[tid] = a;
            sh[tid] = fmaf(-mu, a, bet[tid]);
        }
    }
    // stage Wt: wlds[c][k], row stride 136 u16 (pad 8 -> 2-way bank alias, free)
    for (int i = tid; i < 2048; i += 256) {
        int c = i >> 4, s = i & 15;
        *(uint4*)&wlds[c * 136 + s * 8] = ((const uint4*)wt)[i];
    }
    __syncthreads();

    int lane = tid & 63;
    int wave = tid >> 6;
    int qr = lane >> 4;        // quad: k-offset qr*8
    int rl = lane & 15;        // A row / B col within 16-tile
    int rA0 = row0 + wave * 32 + rl;
    int rA1 = rA0 + 16;
    int rA0c = rA0 < NN ? rA0 : NN - 1;
    int rA1c = rA1 < NN ? rA1 : NN - 1;

    floatx4 acc[2][8];
#pragma unroll
    for (int a = 0; a < 2; a++)
#pragma unroll
        for (int b = 0; b < 8; b++) acc[a][b] = (floatx4){0.f, 0.f, 0.f, 0.f};

#pragma unroll
    for (int kb = 0; kb < 4; kb++) {
        int k0 = kb * 32 + qr * 8;
        short8 a0, a1;
        if (!BF16IN) {
            const float* p0 = (const float*)Xv + (size_t)rA0c * DF + k0;
            const float* p1 = (const float*)Xv + (size_t)rA1c * DF + k0;
            float4 u0 = *(const float4*)p0, u1 = *(const float4*)(p0 + 4);
            float4 v0 = *(const float4*)p1, v1 = *(const float4*)(p1 + 4);
            float fa[8] = {u0.x, u0.y, u0.z, u0.w, u1.x, u1.y, u1.z, u1.w};
            float fb[8] = {v0.x, v0.y, v0.z, v0.w, v1.x, v1.y, v1.z, v1.w};
#pragma unroll
            for (int j = 0; j < 8; j++) { a0[j] = (short)f_to_bf(fa[j]); a1[j] = (short)f_to_bf(fb[j]); }
        } else {
            a0 = *(const short8*)((const u32*)Xv + (size_t)rA0c * 64 + (k0 >> 1));
            a1 = *(const short8*)((const u32*)Xv + (size_t)rA1c * 64 + (k0 >> 1));
            if (FUSE_BN) {
                float4 s0 = *(const float4*)&sc[k0], s1 = *(const float4*)&sc[k0 + 4];
                float4 h0 = *(const float4*)&sh[k0], h1 = *(const float4*)&sh[k0 + 4];
                float ss[8] = {s0.x, s0.y, s0.z, s0.w, s1.x, s1.y, s1.z, s1.w};
                float hh[8] = {h0.x, h0.y, h0.z, h0.w, h1.x, h1.y, h1.z, h1.w};
#pragma unroll
                for (int j = 0; j < 8; j++) {
                    float f0 = fmaxf(fmaf(bf_to_f(a0[j]), ss[j], hh[j]), 0.f);
                    float f1 = fmaxf(fmaf(bf_to_f(a1[j]), ss[j], hh[j]), 0.f);
                    a0[j] = (short)f_to_bf(f0);
                    a1[j] = (short)f_to_bf(f1);
                }
            }
        }
#pragma unroll
        for (int ct = 0; ct < 8; ct++) {
            short8 bfr = *(const short8*)&wlds[(ct * 16 + rl) * 136 + k0];
            acc[0][ct] = __builtin_amdgcn_mfma_f32_16x16x32_bf16(a0, bfr, acc[0][ct], 0, 0, 0);
            acc[1][ct] = __builtin_amdgcn_mfma_f32_16x16x32_bf16(a1, bfr, acc[1][ct], 0, 0, 0);
        }
    }
    __syncthreads();   // all wlds reads done before clds overwrites the union
    // epilogue: C/D layout col=lane&15, row=quad*4+reg -> stage bf16 in LDS, store coalesced
#pragma unroll
    for (int rt = 0; rt < 2; rt++)
#pragma unroll
        for (int ct = 0; ct < 8; ct++)
#pragma unroll
            for (int r = 0; r < 4; r++) {
                int lr = wave * 32 + rt * 16 + qr * 4 + r;
                int c = ct * 16 + rl;
                clds[lr * 136 + c] = (unsigned short)f_to_bf(acc[rt][ct][r]);
            }
    __syncthreads();
    for (int i = tid; i < 2048; i += 256) {
        int lr = i >> 4, s = i & 15;
        int grow = row0 + lr;
        if (grow < NN) {
            uint4 v = *(const uint4*)&clds[lr * 136 + s * 8];
            ((uint4*)(outb + (size_t)grow * 64))[s] = v;
        }
    }
}

// ---------------- CSR fill (2500 blocks) + GEMM1 (313 blocks), merged ----------------
__global__ __launch_bounds__(256, 4) void k_fillgemm(const int* __restrict__ src, const int* __restrict__ dst,
                                                     int* __restrict__ cursor, int* __restrict__ col,
                                                     const float* __restrict__ X, const unsigned short* __restrict__ wt1,
                                                     u32* __restrict__ outb) {
    if (blockIdx.x < NE / 256) {
        int e = blockIdx.x * 256 + threadIdx.x;
        int p = atomicAdd(&cursor[dst[e]], 1);
        col[p] = src[e];
        return;
    }
    gemm_core<false, false>(X, wt1, outb, nullptr, nullptr, nullptr, blockIdx.x - NE / 256);
}

__global__ __launch_bounds__(256, 4) void k_gemm2(const u32* __restrict__ Hb, const unsigned short* __restrict__ wt2,
                                                  u32* __restrict__ outb, const float* __restrict__ slots,
                                                  const float* __restrict__ gam, const float* __restrict__ bet) {
    gemm_core<true, true>(Hb, wt2, outb, slots, gam, bet, blockIdx.x);
}

// ---------------- GCN aggregation: one wave/node, 4 nodes/block; BN-stats fused ----------------
__global__ __launch_bounds__(256) void k_gather(const u32* __restrict__ Hb, const int* __restrict__ row_ptr,
                                                const int* __restrict__ col, const float* __restrict__ dis,
                                                const float* __restrict__ bias, u32* __restrict__ outb,
                                                float* __restrict__ slots) {
    __shared__ float sred[4][128];
    __shared__ float qred[4][128];
    int t = threadIdx.x & 63;                       // lane: cols 2t, 2t+1
    int wv = threadIdx.x >> 6;
    int node = blockIdx.x * 4 + wv;
    float di = dis[node];
    float2 acc;
    {
        float2 a = bf2_to_f2(Hb[(size_t)node * 64 + t]);
        float s = di * di;
        acc = make_float2(a.x * s, a.y * s);
    }
    int lo = row_ptr[node], hi = row_ptr[node + 1];
    for (int base = lo; base < hi; base += 64) {
        int m = hi - base; if (m > 64) m = 64;
        int sidx = 0; float sw = 0.f;
        if (t < m) { sidx = col[base + t]; sw = di * dis[sidx]; }
        int j = 0;
        for (; j + 8 <= m; j += 8) {
            int s0 = __shfl(sidx, j),     s1 = __shfl(sidx, j + 1);
            int s2 = __shfl(sidx, j + 2), s3 = __shfl(sidx, j + 3);
            int s4 = __shfl(sidx, j + 4), s5 = __shfl(sidx, j + 5);
            int s6 = __shfl(sidx, j + 6), s7 = __shfl(sidx, j + 7);
            float w0 = __shfl(sw, j),     w1 = __shfl(sw, j + 1);
            float w2 = __shfl(sw, j + 2), w3 = __shfl(sw, j + 3);
            float w4 = __shfl(sw, j + 4), w5 = __shfl(sw, j + 5);
            float w6 = __shfl(sw, j + 6), w7 = __shfl(sw, j + 7);
            u32 u0 = Hb[(size_t)s0 * 64 + t], u1 = Hb[(size_t)s1 * 64 + t];
            u32 u2 = Hb[(size_t)s2 * 64 + t], u3 = Hb[(size_t)s3 * 64 + t];
            u32 u4 = Hb[(size_t)s4 * 64 + t], u5 = Hb[(size_t)s5 * 64 + t];
            u32 u6 = Hb[(size_t)s6 * 64 + t], u7 = Hb[(size_t)s7 * 64 + t];
            float2 h0 = bf2_to_f2(u0), h1 = bf2_to_f2(u1), h2 = bf2_to_f2(u2), h3 = bf2_to_f2(u3);
            float2 h4 = bf2_to_f2(u4), h5 = bf2_to_f2(u5), h6 = bf2_to_f2(u6), h7 = bf2_to_f2(u7);
            acc.x = fmaf(h3.x, w3, fmaf(h2.x, w2, fmaf(h1.x, w1, fmaf(h0.x, w0, acc.x))));
            acc.y = fmaf(h3.y, w3, fmaf(h2.y, w2, fmaf(h1.y, w1, fmaf(h0.y, w0, acc.y))));
            acc.x = fmaf(h7.x, w7, fmaf(h6.x, w6, fmaf(h5.x, w5, fmaf(h4.x, w4, acc.x))));
            acc.y = fmaf(h7.y, w7, fmaf(h6.y, w6, fmaf(h5.y, w5, fmaf(h4.y, w4, acc.y))));
        }
        for (; j < m; j++) {
            int s0 = __shfl(sidx, j); float w0 = __shfl(sw, j);
            float2 h0 = bf2_to_f2(Hb[(size_t)s0 * 64 + t]);
            acc.x = fmaf(h0.x, w0, acc.x);
            acc.y = fmaf(h0.y, w0, acc.y);
        }
    }
    float2 b = ((const float2*)bias)[t];
    acc.x += b.x; acc.y += b.y;
    outb[(size_t)node * 64 + t] = pack_bf2(acc.x, acc.y);
    // BN stats (pre-BN activations, incl. bias): block reduce -> 64-slot atomics
    sred[wv][2 * t] = acc.x;     sred[wv][2 * t + 1] = acc.y;
    qred[wv][2 * t] = acc.x * acc.x; qred[wv][2 * t + 1] = acc.y * acc.y;
    __syncthreads();
    int tid = threadIdx.x;
    if (tid < 128) {
        float s = sred[0][tid] + sred[1][tid] + sred[2][tid] + sred[3][tid];
        float q = qred[0][tid] + qred[1][tid] + qred[2][tid] + qred[3][tid];
        int slot = blockIdx.x & 63;
        atomicAdd(&slots[slot * 256 + tid], s);
        atomicAdd(&slots[slot * 256 + 128 + tid], q);
    }
}

// ---------------- pool (BN2+ReLU) + fc1 + fc2 + fc3, 4 graphs per block ----------------
__global__ __launch_bounds__(256) void k_poolfc(const u32* __restrict__ Hb, const int* __restrict__ batch,
                                                const float* __restrict__ slots,
                                                const float* __restrict__ gam, const float* __restrict__ bet,
                                                const float* __restrict__ fc1w, const float* __restrict__ fc1b,
                                                const float* __restrict__ fc2w, const float* __restrict__ fc2b,
                                                const float* __restrict__ fc3w, const float* __restrict__ fc3b,
                                                float* __restrict__ out) {
    __shared__ float sc[128], sh[128];
    __shared__ float pooled[4][128];
    __shared__ float g1[4][256];
    __shared__ float g2[4][256];
    __shared__ int bnds[5];
    int tid = threadIdx.x;
    int gbase = blockIdx.x * 4;
    if (tid < 128) {
        float s = 0.f, q = 0.f;
        for (int k = 0; k < 64; k++) {
            s += slots[k * 256 + tid];
            q += slots[k * 256 + 128 + tid];
        }
        const float inv_n = 1.0f / (float)NN;
        float mu = s * inv_n;
        float va = fmaf(-mu, mu, q * inv_n);
        float a = gam[tid] * rsqrtf(va + 1e-5f);
        sc[tid] = a;
        sh[tid] = fmaf(-mu, a, bet[tid]);
    } else if (tid < 133) {
        int target = gbase + (tid - 128);
        int a = 0, b = NN;
        while (a < b) { int m = (a + b) >> 1; if (batch[m] < target) a = m + 1; else b = m; }
        bnds[tid - 128] = a;
    }
    __syncthreads();
    // pooling: wave per graph, lane p -> cols 2p,2p+1
    {
        int g = tid >> 6, p = tid & 63;
        int lo = bnds[g], hi = bnds[g + 1];
        float a0 = 0.f, a1 = 0.f;
        float sc0 = sc[2 * p], sh0 = sh[2 * p], sc1 = sc[2 * p + 1], sh1 = sh[2 * p + 1];
        for (int i = lo; i < hi; i++) {
            float2 v = bf2_to_f2(Hb[(size_t)i * 64 + p]);
            a0 += fmaxf(fmaf(v.x, sc0, sh0), 0.f);
            a1 += fmaxf(fmaf(v.y, sc1, sh1), 0.f);
        }
        pooled[g][2 * p] = a0;
        pooled[g][2 * p + 1] = a1;
    }
    __syncthreads();
    // fc1: K=128 -> 256
    {
        float x0 = 0.f, x1 = 0.f, x2 = 0.f, x3 = 0.f;
        for (int k = 0; k < 128; k++) {
            float wv = fc1w[k * 256 + tid];
            x0 = fmaf(pooled[0][k], wv, x0);
            x1 = fmaf(pooled[1][k], wv, x1);
            x2 = fmaf(pooled[2][k], wv, x2);
            x3 = fmaf(pooled[3][k], wv, x3);
        }
        float bb = fc1b[tid];
        g1[0][tid] = fmaxf(x0 + bb, 0.f);
        g1[1][tid] = fmaxf(x1 + bb, 0.f);
        g1[2][tid] = fmaxf(x2 + bb, 0.f);
        g1[3][tid] = fmaxf(x3 + bb, 0.f);
    }
    __syncthreads();
    // fc2: K=256 -> 256
    {
        float x0 = 0.f, x1 = 0.f, x2 = 0.f, x3 = 0.f;
        for (int k = 0; k < 256; k++) {
            float wv = fc2w[k * 256 + tid];
            x0 = fmaf(g1[0][k], wv, x0);
            x1 = fmaf(g1[1][k], wv, x1);
            x2 = fmaf(g1[2][k], wv, x2);
            x3 = fmaf(g1[3][k], wv, x3);
        }
        float bb = fc2b[tid];
        g2[0][tid] = fmaxf(x0 + bb, 0.f);
        g2[1][tid] = fmaxf(x1 + bb, 0.f);
        g2[2][tid] = fmaxf(x2 + bb, 0.f);
        g2[3][tid] = fmaxf(x3 + bb, 0.f);
    }
    __syncthreads();
    // fc3: wave per graph -> scalar
    {
        int lane = tid & 63, wv = tid >> 6;
        float s = fmaf(g2[wv][lane], fc3w[lane],
                  fmaf(g2[wv][64 + lane], fc3w[64 + lane],
                  fmaf(g2[wv][128 + lane], fc3w[128 + lane],
                       g2[wv][192 + lane] * fc3w[192 + lane])));
        for (int off = 32; off > 0; off >>= 1) s += __shfl_down(s, off);
        if (lane == 0) out[gbase + wv] = s + fc3b[0];
    }
}

extern "C" void kernel_launch(void* const* d_in, const int* in_sizes, int n_in,
                              void* d_out, int out_size, void* d_ws, size_t ws_size,
                              hipStream_t stream) {
    const float* x    = (const float*)d_in[0];
    const int*   ei   = (const int*)d_in[1];
    const int*   batch= (const int*)d_in[2];
    const float* W1   = (const float*)d_in[4];
    const float* b1   = (const float*)d_in[5];
    const float* W2   = (const float*)d_in[6];
    const float* b2   = (const float*)d_in[7];
    const float* bn1g = (const float*)d_in[8];
    const float* bn1b = (const float*)d_in[9];
    const float* bn2g = (const float*)d_in[10];
    const float* bn2b = (const float*)d_in[11];
    const float* fc1w = (const float*)d_in[12];
    const float* fc1b = (const float*)d_in[13];
    const float* fc2w = (const float*)d_in[14];
    const float* fc2b = (const float*)d_in[15];
    const float* fc3w = (const float*)d_in[16];
    const float* fc3b = (const float*)d_in[17];
    const int* src = ei;
    const int* dst = ei + NE;
    float* outp = (float*)d_out;

    char* w = (char*)d_ws;
    size_t o = 0;
    auto alloc = [&](size_t bytes) -> char* {
        char* p = w + o;
        o = (o + bytes + 255) & ~(size_t)255;
        return p;
    };
    // zero region: deg + slotsA + slotsB (contiguous)
    int*   deg     = (int*)alloc((size_t)NN * 4);
    float* slotsA  = (float*)alloc(64 * 256 * 4);
    float* slotsB  = (float*)alloc(64 * 256 * 4);
    char*  zend    = w + o;
    int*   row_ptr = (int*)alloc((size_t)(NN + 1) * 4);
    int*   cursor  = (int*)alloc((size_t)NN * 4);
    int*   col     = (int*)alloc((size_t)NE * 4);
    float* dis     = (float*)alloc((size_t)NN * 4);
    unsigned short* wt1 = (unsigned short*)alloc(128 * 128 * 2);
    unsigned short* wt2 = (unsigned short*)alloc(128 * 128 * 2);
    u32*   bufA    = (u32*)alloc((size_t)NN * 64 * 4);
    u32*   bufB    = (u32*)alloc((size_t)NN * 64 * 4);

    hipMemsetAsync(deg, 0, (size_t)(zend - (char*)deg), stream);

    const int GEMM_BLKS = (NN + 127) / 128;   // 313
    k_count<<<NE / 256 + 2, 256, 0, stream>>>(dst, deg, W1, W2, wt1, wt2);
    k_scan<<<NCH, 256, 0, stream>>>(deg, row_ptr, cursor, dis);
    k_fillgemm<<<NE / 256 + GEMM_BLKS, 256, 0, stream>>>(src, dst, cursor, col, x, wt1, bufA);
    k_gather<<<NN / 4, 256, 0, stream>>>(bufA, row_ptr, col, dis, b1, bufB, slotsA);
    k_gemm2<<<GEMM_BLKS, 256, 0, stream>>>(bufB, wt2, bufA, slotsA, bn1g, bn1b);
    k_gather<<<NN / 4, 256, 0, stream>>>(bufA, row_ptr, col, dis, b2, bufB, slotsB);
    k_poolfc<<<NG / 4, 256, 0, stream>>>(bufB, batch, slotsB, bn2g, bn2b,
                                         fc1w, fc1b, fc2w, fc2b, fc3w, fc3b, outp);
}

// Round 9
// 299.607 us; speedup vs baseline: 2.8355x; 1.0221x over previous
//
#include <hip/hip_runtime.h>

#define NN 40000
#define NE 640000
#define DF 128
#define NG 2000
#define NCH 157        // ceil(NN/256) chunks
#define FILLB 625      // NE / (256*4) edge blocks, 4 edges/thread
#define GEMM_BLKS 313  // ceil(NN/128)

typedef unsigned int u32;
typedef __attribute__((ext_vector_type(8))) short short8;
typedef __attribute__((ext_vector_type(4))) float floatx4;

// ---- bf16 helpers (packed u32: low 16 = even col, high = odd col) ----
__device__ inline float2 bf2_to_f2(u32 u) {
    return make_float2(__uint_as_float(u << 16), __uint_as_float(u & 0xffff0000u));
}
__device__ inline u32 f_to_bf(float f) {
    u32 u = __float_as_uint(f);
    return (u + 0x7fffu + ((u >> 16) & 1u)) >> 16;   // RNE
}
__device__ inline u32 pack_bf2(float a, float b) {
    return f_to_bf(a) | (f_to_bf(b) << 16);
}
__device__ inline float bf_to_f(short s) {
    return __uint_as_float(((u32)(unsigned short)s) << 16);
}

// ---------------- MFMA GEMM core: out[NxDF bf16] = act(X) @ W ----------------
// block 256 thr (4 waves); tile 128 rows x 128 cols; wave w rows w*32..+31, all 128 cols.
// LDS: 34816B wlds/clds union.
// WT_F32: stage W from fp32 row-major global (transpose+convert in-block, no global wt buffer,
//         no cross-block ordering dependency). Else: W pre-transposed bf16 (wt2, written by a
//         PREVIOUS dispatch -- stream order is the barrier).
template<bool BF16IN, bool FUSE_BN, bool WT_F32>
__device__ __forceinline__ void gemm_core(const void* __restrict__ Xv, const void* __restrict__ wsrc,
                                          u32* __restrict__ outb, const float* __restrict__ slots,
                                          const float* __restrict__ gam, const float* __restrict__ bet, int bid) {
    __shared__ unsigned short uni[128 * 136];   // wlds / clds union
    __shared__ float sc[128], sh[128];
    unsigned short* wlds = uni;
    unsigned short* clds = uni;
    int tid = threadIdx.x;
    int row0 = bid * 128;

    if (FUSE_BN) {
        if (tid < 128) {
            float s = 0.f, q = 0.f;
            for (int k = 0; k < 64; k++) {
                s += slots[k * 256 + tid];
                q += slots[k * 256 + 128 + tid];
            }
            const float inv_n = 1.0f / (float)NN;
            float mu = s * inv_n;
            float va = fmaf(-mu, mu, q * inv_n);
            float a = gam[tid] * rsqrtf(va + 1e-5f);
            sc[tid] = a;
            sh[tid] = fmaf(-mu, a, bet[tid]);
        }
    }
    // stage W into wlds[c][k], row stride 136 u16
    if (WT_F32) {
        const float* W = (const float*)wsrc;     // W[k][c] row-major fp32
        for (int i = tid; i < 16384; i += 256) {
            int k = i >> 7, c = i & 127;
            wlds[c * 136 + k] = (unsigned short)f_to_bf(W[i]);
        }
    } else {
        const unsigned short* wt = (const unsigned short*)wsrc;   // pre-transposed bf16
        for (int i = tid; i < 2048; i += 256) {
            int c = i >> 4, s = i & 15;
            *(uint4*)&wlds[c * 136 + s * 8] = ((const uint4*)wt)[i];
        }
    }
    __syncthreads();

    int lane = tid & 63;
    int wave = tid >> 6;
    int qr = lane >> 4;        // quad: k-offset qr*8
    int rl = lane & 15;        // A row / B col within 16-tile
    int rA0 = row0 + wave * 32 + rl;
    int rA1 = rA0 + 16;
    int rA0c = rA0 < NN ? rA0 : NN - 1;
    int rA1c = rA1 < NN ? rA1 : NN - 1;

    floatx4 acc[2][8];
#pragma unroll
    for (int a = 0; a < 2; a++)
#pragma unroll
        for (int b = 0; b < 8; b++) acc[a][b] = (floatx4){0.f, 0.f, 0.f, 0.f};

#pragma unroll
    for (int kb = 0; kb < 4; kb++) {
        int k0 = kb * 32 + qr * 8;
        short8 a0, a1;
        if (!BF16IN) {
            const float* p0 = (const float*)Xv + (size_t)rA0c * DF + k0;
            const float* p1 = (const float*)Xv + (size_t)rA1c * DF + k0;
            float4 u0 = *(const float4*)p0, u1 = *(const float4*)(p0 + 4);
            float4 v0 = *(const float4*)p1, v1 = *(const float4*)(p1 + 4);
            float fa[8] = {u0.x, u0.y, u0.z, u0.w, u1.x, u1.y, u1.z, u1.w};
            float fb[8] = {v0.x, v0.y, v0.z, v0.w, v1.x, v1.y, v1.z, v1.w};
#pragma unroll
            for (int j = 0; j < 8; j++) { a0[j] = (short)f_to_bf(fa[j]); a1[j] = (short)f_to_bf(fb[j]); }
        } else {
            a0 = *(const short8*)((const u32*)Xv + (size_t)rA0c * 64 + (k0 >> 1));
            a1 = *(const short8*)((const u32*)Xv + (size_t)rA1c * 64 + (k0 >> 1));
            if (FUSE_BN) {
                float4 s0 = *(const float4*)&sc[k0], s1 = *(const float4*)&sc[k0 + 4];
                float4 h0 = *(const float4*)&sh[k0], h1 = *(const float4*)&sh[k0 + 4];
                float ss[8] = {s0.x, s0.y, s0.z, s0.w, s1.x, s1.y, s1.z, s1.w};
                float hh[8] = {h0.x, h0.y, h0.z, h0.w, h1.x, h1.y, h1.z, h1.w};
#pragma unroll
                for (int j = 0; j < 8; j++) {
                    float f0 = fmaxf(fmaf(bf_to_f(a0[j]), ss[j], hh[j]), 0.f);
                    float f1 = fmaxf(fmaf(bf_to_f(a1[j]), ss[j], hh[j]), 0.f);
                    a0[j] = (short)f_to_bf(f0);
                    a1[j] = (short)f_to_bf(f1);
                }
            }
        }
#pragma unroll
        for (int ct = 0; ct < 8; ct++) {
            short8 bfr = *(const short8*)&wlds[(ct * 16 + rl) * 136 + k0];
            acc[0][ct] = __builtin_amdgcn_mfma_f32_16x16x32_bf16(a0, bfr, acc[0][ct], 0, 0, 0);
            acc[1][ct] = __builtin_amdgcn_mfma_f32_16x16x32_bf16(a1, bfr, acc[1][ct], 0, 0, 0);
        }
    }
    __syncthreads();   // all wlds reads done before clds overwrites the union
    // epilogue: C/D layout col=lane&15, row=quad*4+reg -> stage bf16 in LDS, store coalesced
#pragma unroll
    for (int rt = 0; rt < 2; rt++)
#pragma unroll
        for (int ct = 0; ct < 8; ct++)
#pragma unroll
            for (int r = 0; r < 4; r++) {
                int lr = wave * 32 + rt * 16 + qr * 4 + r;
                int c = ct * 16 + rl;
                clds[lr * 136 + c] = (unsigned short)f_to_bf(acc[rt][ct][r]);
            }
    __syncthreads();
    for (int i = tid; i < 2048; i += 256) {
        int lr = i >> 4, s = i & 15;
        int grow = row0 + lr;
        if (grow < NN) {
            uint4 v = *(const uint4*)&clds[lr * 136 + s * 8];
            ((uint4*)(outb + (size_t)grow * 64))[s] = v;
        }
    }
}

// ---------------- count (625 blocks, 4 edges/thread) + wt2 transpose (1) + GEMM1 (313) ----------------
// GEMM1 stages W1 from fp32 directly (no wt1) -> no intra-grid producer/consumer race.
__global__ __launch_bounds__(256, 4) void k_countgemm(const int* __restrict__ dst, int* __restrict__ deg,
                                                      const float* __restrict__ W1, const float* __restrict__ W2,
                                                      unsigned short* __restrict__ wt2,
                                                      const float* __restrict__ X, u32* __restrict__ outb) {
    int bid = blockIdx.x;
    if (bid < FILLB) {
        int e0 = bid * 1024 + threadIdx.x;
        int d0 = dst[e0], d1 = dst[e0 + 256], d2 = dst[e0 + 512], d3 = dst[e0 + 768];
        atomicAdd(&deg[d0], 1);
        atomicAdd(&deg[d1], 1);
        atomicAdd(&deg[d2], 1);
        atomicAdd(&deg[d3], 1);
        return;
    }
    if (bid == FILLB) {
        for (int i = threadIdx.x; i < 128 * 128; i += 256) {
            int k = i >> 7, c = i & 127;
            wt2[c * 128 + k] = (unsigned short)f_to_bf(W2[i]);   // consumed by k_gemm2 (later dispatch)
        }
        return;
    }
    gemm_core<false, false, true>(X, W1, outb, nullptr, nullptr, nullptr, bid - FILLB - 1);
}

// ---------------- scan: 157 blocks; block b redundantly sums deg[0..256b) ----------------
__global__ __launch_bounds__(256) void k_scan(const int* __restrict__ deg,
                                              int* __restrict__ row_ptr, int* __restrict__ cursor,
                                              float* __restrict__ dis) {
    __shared__ int red[256];
    __shared__ int ls[256];
    int tid = threadIdx.x;
    int blk = blockIdx.x;
    int limit = blk * 256;
    int partial = 0;
    for (int i = tid; i < limit; i += 256) partial += deg[i];
    red[tid] = partial;
    int i = limit + tid;
    int d = (i < NN) ? deg[i] : 0;
    ls[tid] = d;
    __syncthreads();
#pragma unroll
    for (int off = 128; off > 0; off >>= 1) {
        if (tid < off) red[tid] += red[tid + off];
        __syncthreads();
    }
    int base = red[0];
#pragma unroll
    for (int off = 1; off < 256; off <<= 1) {
        int t = (tid >= off) ? ls[tid - off] : 0;
        __syncthreads();
        ls[tid] += t;
        __syncthreads();
    }
    if (i < NN) {
        int r = base + ls[tid] - d;   // global exclusive prefix
        row_ptr[i] = r;
        cursor[i] = r;
        dis[i] = rsqrtf((float)(d + 1));
    }
    if (blk == NCH - 1 && tid == 0) row_ptr[NN] = NE;
}

// ---------------- CSR fill: standalone, high occupancy, 4 edges/thread ----------------
__global__ __launch_bounds__(256) void k_fill(const int* __restrict__ src, const int* __restrict__ dst,
                                              int* __restrict__ cursor, int* __restrict__ col) {
    int e0 = blockIdx.x * 1024 + threadIdx.x;
    int d0 = dst[e0], d1 = dst[e0 + 256], d2 = dst[e0 + 512], d3 = dst[e0 + 768];
    int s0 = src[e0], s1 = src[e0 + 256], s2 = src[e0 + 512], s3 = src[e0 + 768];
    int p0 = atomicAdd(&cursor[d0], 1);
    int p1 = atomicAdd(&cursor[d1], 1);
    int p2 = atomicAdd(&cursor[d2], 1);
    int p3 = atomicAdd(&cursor[d3], 1);
    col[p0] = s0;
    col[p1] = s1;
    col[p2] = s2;
    col[p3] = s3;
}

__global__ __launch_bounds__(256, 4) void k_gemm2(const u32* __restrict__ Hb, const unsigned short* __restrict__ wt2,
                                                  u32* __restrict__ outb, const float* __restrict__ slots,
                                                  const float* __restrict__ gam, const float* __restrict__ bet) {
    gemm_core<true, true, false>(Hb, wt2, outb, slots, gam, bet, blockIdx.x);
}

// ---------------- GCN aggregation: one wave/node, 4 nodes/block; BN-stats fused ----------------
__global__ __launch_bounds__(256) void k_gather(const u32* __restrict__ Hb, const int* __restrict__ row_ptr,
                                                const int* __restrict__ col, const float* __restrict__ dis,
                                                const float* __restrict__ bias, u32* __restrict__ outb,
                                                float* __restrict__ slots) {
    __shared__ float sred[4][128];
    __shared__ float qred[4][128];
    int t = threadIdx.x & 63;                       // lane: cols 2t, 2t+1
    int wv = threadIdx.x >> 6;
    int node = blockIdx.x * 4 + wv;
    float di = dis[node];
    float2 acc;
    {
        float2 a = bf2_to_f2(Hb[(size_t)node * 64 + t]);
        float s = di * di;
        acc = make_float2(a.x * s, a.y * s);
    }
    int lo = row_ptr[node], hi = row_ptr[node + 1];
    for (int base = lo; base < hi; base += 64) {
        int m = hi - base; if (m > 64) m = 64;
        int sidx = 0; float sw = 0.f;
        if (t < m) { sidx = col[base + t]; sw = di * dis[sidx]; }
        int j = 0;
        for (; j + 8 <= m; j += 8) {
            int s0 = __shfl(sidx, j),     s1 = __shfl(sidx, j + 1);
            int s2 = __shfl(sidx, j + 2), s3 = __shfl(sidx, j + 3);
            int s4 = __shfl(sidx, j + 4), s5 = __shfl(sidx, j + 5);
            int s6 = __shfl(sidx, j + 6), s7 = __shfl(sidx, j + 7);
            float w0 = __shfl(sw, j),     w1 = __shfl(sw, j + 1);
            float w2 = __shfl(sw, j + 2), w3 = __shfl(sw, j + 3);
            float w4 = __shfl(sw, j + 4), w5 = __shfl(sw, j + 5);
            float w6 = __shfl(sw, j + 6), w7 = __shfl(sw, j + 7);
            u32 u0 = Hb[(size_t)s0 * 64 + t], u1 = Hb[(size_t)s1 * 64 + t];
            u32 u2 = Hb[(size_t)s2 * 64 + t], u3 = Hb[(size_t)s3 * 64 + t];
            u32 u4 = Hb[(size_t)s4 * 64 + t], u5 = Hb[(size_t)s5 * 64 + t];
            u32 u6 = Hb[(size_t)s6 * 64 + t], u7 = Hb[(size_t)s7 * 64 + t];
            float2 h0 = bf2_to_f2(u0), h1 = bf2_to_f2(u1), h2 = bf2_to_f2(u2), h3 = bf2_to_f2(u3);
            float2 h4 = bf2_to_f2(u4), h5 = bf2_to_f2(u5), h6 = bf2_to_f2(u6), h7 = bf2_to_f2(u7);
            acc.x = fmaf(h3.x, w3, fmaf(h2.x, w2, fmaf(h1.x, w1, fmaf(h0.x, w0, acc.x))));
            acc.y = fmaf(h3.y, w3, fmaf(h2.y, w2, fmaf(h1.y, w1, fmaf(h0.y, w0, acc.y))));
            acc.x = fmaf(h7.x, w7, fmaf(h6.x, w6, fmaf(h5.x, w5, fmaf(h4.x, w4, acc.x))));
            acc.y = fmaf(h7.y, w7, fmaf(h6.y, w6, fmaf(h5.y, w5, fmaf(h4.y, w4, acc.y))));
        }
        for (; j < m; j++) {
            int s0 = __shfl(sidx, j); float w0 = __shfl(sw, j);
            float2 h0 = bf2_to_f2(Hb[(size_t)s0 * 64 + t]);
            acc.x = fmaf(h0.x, w0, acc.x);
            acc.y = fmaf(h0.y, w0, acc.y);
        }
    }
    float2 b = ((const float2*)bias)[t];
    acc.x += b.x; acc.y += b.y;
    outb[(size_t)node * 64 + t] = pack_bf2(acc.x, acc.y);
    // BN stats (pre-BN activations, incl. bias): block reduce -> 64-slot atomics
    sred[wv][2 * t] = acc.x;     sred[wv][2 * t + 1] = acc.y;
    qred[wv][2 * t] = acc.x * acc.x; qred[wv][2 * t + 1] = acc.y * acc.y;
    __syncthreads();
    int tid = threadIdx.x;
    if (tid < 128) {
        float s = sred[0][tid] + sred[1][tid] + sred[2][tid] + sred[3][tid];
        float q = qred[0][tid] + qred[1][tid] + qred[2][tid] + qred[3][tid];
        int slot = blockIdx.x & 63;
        atomicAdd(&slots[slot * 256 + tid], s);
        atomicAdd(&slots[slot * 256 + 128 + tid], q);
    }
}

// ---------------- pool (BN2+ReLU) + fc1 + fc2 + fc3, 4 graphs per block ----------------
__global__ __launch_bounds__(256) void k_poolfc(const u32* __restrict__ Hb, const int* __restrict__ batch,
                                                const float* __restrict__ slots,
                                                const float* __restrict__ gam, const float* __restrict__ bet,
                                                const float* __restrict__ fc1w, const float* __restrict__ fc1b,
                                                const float* __restrict__ fc2w, const float* __restrict__ fc2b,
                                                const float* __restrict__ fc3w, const float* __restrict__ fc3b,
                                                float* __restrict__ out) {
    __shared__ float sc[128], sh[128];
    __shared__ float pooled[4][128];
    __shared__ float g1[4][256];
    __shared__ float g2[4][256];
    __shared__ int bnds[5];
    int tid = threadIdx.x;
    int gbase = blockIdx.x * 4;
    if (tid < 128) {
        float s = 0.f, q = 0.f;
        for (int k = 0; k < 64; k++) {
            s += slots[k * 256 + tid];
            q += slots[k * 256 + 128 + tid];
        }
        const float inv_n = 1.0f / (float)NN;
        float mu = s * inv_n;
        float va = fmaf(-mu, mu, q * inv_n);
        float a = gam[tid] * rsqrtf(va + 1e-5f);
        sc[tid] = a;
        sh[tid] = fmaf(-mu, a, bet[tid]);
    } else if (tid < 133) {
        int target = gbase + (tid - 128);
        int a = 0, b = NN;
        while (a < b) { int m = (a + b) >> 1; if (batch[m] < target) a = m + 1; else b = m; }
        bnds[tid - 128] = a;
    }
    __syncthreads();
    // pooling: wave per graph, lane p -> cols 2p,2p+1
    {
        int g = tid >> 6, p = tid & 63;
        int lo = bnds[g], hi = bnds[g + 1];
        float a0 = 0.f, a1 = 0.f;
        float sc0 = sc[2 * p], sh0 = sh[2 * p], sc1 = sc[2 * p + 1], sh1 = sh[2 * p + 1];
        for (int i = lo; i < hi; i++) {
            float2 v = bf2_to_f2(Hb[(size_t)i * 64 + p]);
            a0 += fmaxf(fmaf(v.x, sc0, sh0), 0.f);
            a1 += fmaxf(fmaf(v.y, sc1, sh1), 0.f);
        }
        pooled[g][2 * p] = a0;
        pooled[g][2 * p + 1] = a1;
    }
    __syncthreads();
    // fc1: K=128 -> 256
    {
        float x0 = 0.f, x1 = 0.f, x2 = 0.f, x3 = 0.f;
        for (int k = 0; k < 128; k++) {
            float wv = fc1w[k * 256 + tid];
            x0 = fmaf(pooled[0][k], wv, x0);
            x1 = fmaf(pooled[1][k], wv, x1);
            x2 = fmaf(pooled[2][k], wv, x2);
            x3 = fmaf(pooled[3][k], wv, x3);
        }
        float bb = fc1b[tid];
        g1[0][tid] = fmaxf(x0 + bb, 0.f);
        g1[1][tid] = fmaxf(x1 + bb, 0.f);
        g1[2][tid] = fmaxf(x2 + bb, 0.f);
        g1[3][tid] = fmaxf(x3 + bb, 0.f);
    }
    __syncthreads();
    // fc2: K=256 -> 256
    {
        float x0 = 0.f, x1 = 0.f, x2 = 0.f, x3 = 0.f;
        for (int k = 0; k < 256; k++) {
            float wv = fc2w[k * 256 + tid];
            x0 = fmaf(g1[0][k], wv, x0);
            x1 = fmaf(g1[1][k], wv, x1);
            x2 = fmaf(g1[2][k], wv, x2);
            x3 = fmaf(g1[3][k], wv, x3);
        }
        float bb = fc2b[tid];
        g2[0][tid] = fmaxf(x0 + bb, 0.f);
        g2[1][tid] = fmaxf(x1 + bb, 0.f);
        g2[2][tid] = fmaxf(x2 + bb, 0.f);
        g2[3][tid] = fmaxf(x3 + bb, 0.f);
    }
    __syncthreads();
    // fc3: wave per graph -> scalar
    {
        int lane = tid & 63, wv = tid >> 6;
        float s = fmaf(g2[wv][lane], fc3w[lane],
                  fmaf(g2[wv][64 + lane], fc3w[64 + lane],
                  fmaf(g2[wv][128 + lane], fc3w[128 + lane],
                       g2[wv][192 + lane] * fc3w[192 + lane])));
        for (int off = 32; off > 0; off >>= 1) s += __shfl_down(s, off);
        if (lane == 0) out[gbase + wv] = s + fc3b[0];
    }
}

extern "C" void kernel_launch(void* const* d_in, const int* in_sizes, int n_in,
                              void* d_out, int out_size, void* d_ws, size_t ws_size,
                              hipStream_t stream) {
    const float* x    = (const float*)d_in[0];
    const int*   ei   = (const int*)d_in[1];
    const int*   batch= (const int*)d_in[2];
    const float* W1   = (const float*)d_in[4];
    const float* b1   = (const float*)d_in[5];
    const float* W2   = (const float*)d_in[6];
    const float* b2   = (const float*)d_in[7];
    const float* bn1g = (const float*)d_in[8];
    const float* bn1b = (const float*)d_in[9];
    const float* bn2g = (const float*)d_in[10];
    const float* bn2b = (const float*)d_in[11];
    const float* fc1w = (const float*)d_in[12];
    const float* fc1b = (const float*)d_in[13];
    const float* fc2w = (const float*)d_in[14];
    const float* fc2b = (const float*)d_in[15];
    const float* fc3w = (const float*)d_in[16];
    const float* fc3b = (const float*)d_in[17];
    const int* src = ei;
    const int* dst = ei + NE;
    float* outp = (float*)d_out;

    char* w = (char*)d_ws;
    size_t o = 0;
    auto alloc = [&](size_t bytes) -> char* {
        char* p = w + o;
        o = (o + bytes + 255) & ~(size_t)255;
        return p;
    };
    // zero region: deg + slotsA + slotsB (contiguous)
    int*   deg     = (int*)alloc((size_t)NN * 4);
    float* slotsA  = (float*)alloc(64 * 256 * 4);
    float* slotsB  = (float*)alloc(64 * 256 * 4);
    char*  zend    = w + o;
    int*   row_ptr = (int*)alloc((size_t)(NN + 1) * 4);
    int*   cursor  = (int*)alloc((size_t)NN * 4);
    int*   col     = (int*)alloc((size_t)NE * 4);
    float* dis     = (float*)alloc((size_t)NN * 4);
    unsigned short* wt2 = (unsigned short*)alloc(128 * 128 * 2);
    u32*   bufA    = (u32*)alloc((size_t)NN * 64 * 4);
    u32*   bufB    = (u32*)alloc((size_t)NN * 64 * 4);

    hipMemsetAsync(deg, 0, (size_t)(zend - (char*)deg), stream);

    k_countgemm<<<FILLB + 1 + GEMM_BLKS, 256, 0, stream>>>(dst, deg, W1, W2, wt2, x, bufA);
    k_scan<<<NCH, 256, 0, stream>>>(deg, row_ptr, cursor, dis);
    k_fill<<<FILLB, 256, 0, stream>>>(src, dst, cursor, col);
    k_gather<<<NN / 4, 256, 0, stream>>>(bufA, row_ptr, col, dis, b1, bufB, slotsA);
    k_gemm2<<<GEMM_BLKS, 256, 0, stream>>>(bufB, wt2, bufA, slotsA, bn1g, bn1b);
    k_gather<<<NN / 4, 256, 0, stream>>>(bufA, row_ptr, col, dis, b2, bufB, slotsB);
    k_poolfc<<<NG / 4, 256, 0, stream>>>(bufB, batch, slotsB, bn2g, bn2b,
                                         fc1w, fc1b, fc2w, fc2b, fc3w, fc3b, outp);
}